// Round 19
// baseline (273.555 us; speedup 1.0000x reference)
//
#include <hip/hip_runtime.h>
#include <math.h>

#define DE 128
#define NEG_SLOPE 0.2f
#define LOG2E 1.4426950408889634f
#define ESHIFT2 57.707801635559926f      /* 40 * log2(e)  (entity) */
#define ESHIFT_AGG 28.853900817779268f   /* 20 * log2(e)  (aggregate) */
#define EXP2(x) __builtin_amdgcn_exp2f(x)  /* raw v_exp_f32; inputs bounded */

typedef __attribute__((ext_vector_type(4))) float f4;
typedef __attribute__((ext_vector_type(2))) float f2;
typedef _Float16 half_t;
typedef __attribute__((ext_vector_type(2))) _Float16 h2;
typedef __attribute__((ext_vector_type(4))) _Float16 h4v;
typedef __attribute__((ext_vector_type(8))) _Float16 h8;

// Wave64 sum-reduce on the VALU only (DPP adds + readlane), zero LDS-pipe ops.
__device__ __forceinline__ float wave_red_bcast(float x) {
    union fi { float f; int i; };
    fi a; a.f = x;
    fi t;
    t.i = __builtin_amdgcn_update_dpp(0, a.i, 0x111, 0xf, 0xf, true); a.f += t.f; // row_shr:1
    t.i = __builtin_amdgcn_update_dpp(0, a.i, 0x112, 0xf, 0xf, true); a.f += t.f; // row_shr:2
    t.i = __builtin_amdgcn_update_dpp(0, a.i, 0x114, 0xf, 0xf, true); a.f += t.f; // row_shr:4
    t.i = __builtin_amdgcn_update_dpp(0, a.i, 0x118, 0xf, 0xf, true); a.f += t.f; // row_shr:8
    t.i = __builtin_amdgcn_update_dpp(0, a.i, 0x142, 0xa, 0xf, true); a.f += t.f; // row_bcast:15
    t.i = __builtin_amdgcn_update_dpp(0, a.i, 0x143, 0xc, 0xf, true); a.f += t.f; // row_bcast:31
    fi r; r.i = __builtin_amdgcn_readlane(a.i, 63);
    return r.f;
}

// All-reduce within each 16-lane DPP row (lane gets its row's sum). 4 DPP adds.
__device__ __forceinline__ float row16_allred(float x) {
    union fi { float f; int i; };
    fi a; a.f = x;
    fi t;
    t.i = __builtin_amdgcn_update_dpp(0, a.i, 0x121, 0xf, 0xf, true); a.f += t.f; // row_ror:1
    t.i = __builtin_amdgcn_update_dpp(0, a.i, 0x122, 0xf, 0xf, true); a.f += t.f; // row_ror:2
    t.i = __builtin_amdgcn_update_dpp(0, a.i, 0x124, 0xf, 0xf, true); a.f += t.f; // row_ror:4
    t.i = __builtin_amdgcn_update_dpp(0, a.i, 0x128, 0xf, 0xf, true); a.f += t.f; // row_ror:8
    return a.f;
}

// ================================================================ CSR bodies
// count ALSO records each edge's rank among same-dst edges (atomic return value)
// -> fill needs NO atomics at all.
__device__ __forceinline__ void count_body(int bid, const int* __restrict__ ei, int E, int N,
                                           int* __restrict__ cnt, int* __restrict__ rank) {
    int e = bid * 256 + threadIdx.x;
    int total = E + N;
    if (e >= total) return;
    int dst = (e < E) ? ei[E + e] : (e - E);
    rank[e] = atomicAdd(&cnt[dst], 1);  // rank write is coalesced (indexed by e)
}

// 256-thread block scan, 4 items/thread per 1024-tile. smem: >= 5 ints.
__device__ void scan_body(const int* __restrict__ cnt, int n, int* __restrict__ indptr,
                          char* smem) {
    int* wsum = (int*)smem;       // [4]
    int* btot = (int*)smem + 4;
    const int tid = threadIdx.x, lane = tid & 63, w = tid >> 6;
    int carry = 0;
    for (int base = 0; base < n; base += 1024) {
        int i0 = base + tid * 4;
        int4 v = {0, 0, 0, 0};
        if (i0 + 3 < n) v = *(const int4*)(cnt + i0);
        else {
            if (i0 < n)     v.x = cnt[i0];
            if (i0 + 1 < n) v.y = cnt[i0 + 1];
            if (i0 + 2 < n) v.z = cnt[i0 + 2];
        }
        int s = v.x + v.y + v.z + v.w;
        int x = s;
#pragma unroll
        for (int off = 1; off < 64; off <<= 1) {
            int t = __shfl_up(x, off, 64);
            if (lane >= off) x += t;
        }
        if (lane == 63) wsum[w] = x;
        __syncthreads();
        if (tid == 0) {
            int acc = 0;
#pragma unroll
            for (int k = 0; k < 4; ++k) { int t = wsum[k]; wsum[k] = acc; acc += t; }
            *btot = acc;
        }
        __syncthreads();
        int excl = carry + wsum[w] + (x - s);
        if (i0 < n)     indptr[i0]     = excl;
        if (i0 + 1 < n) indptr[i0 + 1] = excl + v.x;
        if (i0 + 2 < n) indptr[i0 + 2] = excl + v.x + v.y;
        if (i0 + 3 < n) indptr[i0 + 3] = excl + v.x + v.y + v.z;
        carry += *btot;
        __syncthreads();
    }
    if (tid == 0) indptr[n] = carry;
}

// atomic-free fill: pos = indptr[dst] + rank[e]
__device__ __forceinline__ void fill_body(int bid, const int* __restrict__ ei, int E, int N,
                                          const int* __restrict__ indptr,
                                          const int* __restrict__ rank,
                                          int* __restrict__ adj) {
    int e = bid * 256 + threadIdx.x;
    int total = E + N;
    if (e >= total) return;
    int src, dst;
    if (e < E) { src = ei[e]; dst = ei[E + e]; }
    else       { src = dst = e - E; }
    adj[indptr[dst] + rank[e]] = src;
}

// ================================================================ rel-table GEMM body (500 rows)
__device__ void rel_body(int bx, int sel, const float* __restrict__ in, int rows,
                         const float* __restrict__ W1, const float* __restrict__ bias1,
                         float* __restrict__ out1, const float* __restrict__ W2,
                         float* __restrict__ out2, char* smem) {
    const float* W; int ldw, wcol0; const float* bias; float* out;
    if (sel == 0) { W = W1; ldw = DE;     wcol0 = 0;  bias = bias1;   out = out1; }
    else          { W = W2; ldw = 2 * DE; wcol0 = DE; bias = nullptr; out = out2; }

    float* Wt = (float*)smem;  // [128*128]
    const int tid = threadIdx.x;
#pragma unroll
    for (int it = 0; it < 16; ++it) {
        int idx = it * 256 + tid;
        int c = idx & 127, k4 = idx >> 7;
        f4 wv = *(const f4*)(W + (size_t)c * ldw + wcol0 + k4 * 4);
#pragma unroll
        for (int j = 0; j < 4; ++j) Wt[(4 * k4 + j) * 128 + c] = wv[j];
    }
    __syncthreads();

    const int RPT = 2;
    const int cgrp = tid & 15, rgrp = tid >> 4;
    const int c0 = cgrp * 4;
    const int row0 = bx * (16 * RPT) + rgrp * RPT;

    const float* rowp[RPT];
#pragma unroll
    for (int i = 0; i < RPT; ++i)
        rowp[i] = in + (size_t)min(row0 + i, rows - 1) * 128;

    float acc[RPT][8];
#pragma unroll
    for (int i = 0; i < RPT; ++i)
#pragma unroll
        for (int j = 0; j < 8; ++j) acc[i][j] = 0.f;

#pragma unroll 1
    for (int k = 0; k < 128; k += 4) {
        f4 a[RPT];
#pragma unroll
        for (int i = 0; i < RPT; ++i) a[i] = *(const f4*)(rowp[i] + k);
#pragma unroll
        for (int kk = 0; kk < 4; ++kk) {
            f4 b0 = *(const f4*)&Wt[(k + kk) * 128 + c0];
            f4 b1 = *(const f4*)&Wt[(k + kk) * 128 + c0 + 64];
#pragma unroll
            for (int i = 0; i < RPT; ++i) {
                float av = a[i][kk];
#pragma unroll
                for (int j = 0; j < 4; ++j) {
                    acc[i][j]     = fmaf(av, b0[j], acc[i][j]);
                    acc[i][j + 4] = fmaf(av, b1[j], acc[i][j + 4]);
                }
            }
        }
    }
    f4 bi0 = {0.f,0.f,0.f,0.f}, bi1 = {0.f,0.f,0.f,0.f};
    if (bias) { bi0 = *(const f4*)(bias + c0); bi1 = *(const f4*)(bias + c0 + 64); }
#pragma unroll
    for (int i = 0; i < RPT; ++i) {
        int r = row0 + i;
        if (r < rows) {
            f4 v0, v1;
#pragma unroll
            for (int j = 0; j < 4; ++j) { v0[j] = acc[i][j] + bi0[j]; v1[j] = acc[i][j+4] + bi1[j]; }
            *(f4*)(out + (size_t)r * 128 + c0) = v0;
            *(f4*)(out + (size_t)r * 128 + c0 + 64) = v1;
        }
    }
}

// ================================================================ MFMA GEMM body (fp16 in, f32 acc)
// als/ald stored PRE-SCALED by log2(e). smem: 128*136*2 bytes.
template <typename AT>
__device__ void gemm_mfma_body(int bid, const AT* __restrict__ A, int rows,
                               const float* __restrict__ W, int ldw, int wcol0,
                               const float* __restrict__ bias,
                               const float* __restrict__ addtab,
                               const int* __restrict__ addidx,
                               const float* __restrict__ avs,
                               const float* __restrict__ avd,
                               float* __restrict__ als,
                               float* __restrict__ ald,
                               half_t* __restrict__ out16, char* smem) {
    half_t* Wl = (half_t*)smem;
    float*  Dl = (float*)smem;

    const int tid = threadIdx.x;
    const int row0 = bid * 64;

    for (int i = tid * 4; i < 128 * 128; i += 1024) {
        int c = i >> 7, k = i & 127;
        f4 wv = *(const f4*)(W + (size_t)c * ldw + wcol0 + k);
        h4v hv = {(half_t)wv[0], (half_t)wv[1], (half_t)wv[2], (half_t)wv[3]};
        *(h4v*)(Wl + c * 136 + k) = hv;
    }
    __syncthreads();

    const int wv_id = tid >> 6, l = tid & 63, lr = l & 15, lk = l >> 4;
    const int r_a = min(row0 + wv_id * 16 + lr, rows - 1);

    h8 af[4];
#pragma unroll
    for (int ks = 0; ks < 4; ++ks) {
        if constexpr (sizeof(AT) == 4) {
            f4 a0 = *(const f4*)(A + (size_t)r_a * 128 + ks * 32 + lk * 8);
            f4 a1 = *(const f4*)(A + (size_t)r_a * 128 + ks * 32 + lk * 8 + 4);
            h8 v = {(half_t)a0[0], (half_t)a0[1], (half_t)a0[2], (half_t)a0[3],
                    (half_t)a1[0], (half_t)a1[1], (half_t)a1[2], (half_t)a1[3]};
            af[ks] = v;
        } else {
            af[ks] = *(const h8*)(A + (size_t)r_a * 128 + ks * 32 + lk * 8);
        }
    }

    f4 acc[8];
#pragma unroll
    for (int t = 0; t < 8; ++t) acc[t] = (f4){0.f, 0.f, 0.f, 0.f};
#pragma unroll
    for (int ks = 0; ks < 4; ++ks) {
#pragma unroll
        for (int t = 0; t < 8; ++t) {
            h8 bf = *(const h8*)(Wl + (t * 16 + lr) * 136 + ks * 32 + lk * 8);
            acc[t] = __builtin_amdgcn_mfma_f32_16x16x32_f16(af[ks], bf, acc[t], 0, 0, 0);
        }
    }
    __syncthreads();

#pragma unroll
    for (int t = 0; t < 8; ++t)
#pragma unroll
        for (int q = 0; q < 4; ++q)
            Dl[(wv_id * 16 + lk * 4 + q) * 132 + t * 16 + lr] = acc[t][q];
    __syncthreads();

    const int cl = (tid & 15) * 8;
    f4 bi0 = {0.f,0.f,0.f,0.f}, bi1 = bi0;
    if (bias) { bi0 = *(const f4*)(bias + cl); bi1 = *(const f4*)(bias + cl + 4); }
    f4 as0 = {0.f,0.f,0.f,0.f}, as1 = as0, ad0 = as0, ad1 = as0;
    if (als) {
        as0 = *(const f4*)(avs + cl) * LOG2E; as1 = *(const f4*)(avs + cl + 4) * LOG2E;
        ad0 = *(const f4*)(avd + cl) * LOG2E; ad1 = *(const f4*)(avd + cl + 4) * LOG2E;
    }
#pragma unroll
    for (int pass = 0; pass < 4; ++pass) {
        int lrow = pass * 16 + (tid >> 4);
        int r = row0 + lrow;
        bool ok = r < rows;
        f4 v0 = *(const f4*)(Dl + lrow * 132 + cl);
        f4 v1 = *(const f4*)(Dl + lrow * 132 + cl + 4);
        v0 += bi0; v1 += bi1;
        if (addtab) {
            int ri = addidx[min(r, rows - 1)];
            v0 += *(const f4*)(addtab + (size_t)ri * 128 + cl);
            v1 += *(const f4*)(addtab + (size_t)ri * 128 + cl + 4);
        }
        if (als) {
            float ps = 0.f, pd = 0.f;
#pragma unroll
            for (int j = 0; j < 4; ++j) {
                ps += v0[j] * as0[j] + v1[j] * as1[j];
                pd += v0[j] * ad0[j] + v1[j] * ad1[j];
            }
            ps = row16_allred(ps);
            pd = row16_allred(pd);
            if ((tid & 15) == 0 && ok) { als[r] = ps; ald[r] = pd; }
        }
        if (ok) {
            h8 o = {(half_t)v0[0], (half_t)v0[1], (half_t)v0[2], (half_t)v0[3],
                    (half_t)v1[0], (half_t)v1[1], (half_t)v1[2], (half_t)v1[3]};
            *(h8*)(out16 + (size_t)r * 128 + cl) = o;
        }
    }
}

// ================================================================ entity body (FROZEN structure)
__device__ void entity_body(int bid, const int* __restrict__ hA,
                            const int* __restrict__ tA,
                            const int* __restrict__ ridx,
                            const half_t* __restrict__ pattr,
                            const float* __restrict__ prel,
                            half_t* __restrict__ s_emb16, int N) {
    int w = (bid * 256 + (int)threadIdx.x) >> 6;
    if (w >= N) return;
    w = __builtin_amdgcn_readfirstlane(w);
    const int lane = threadIdx.x & 63;
    const int c = lane * 2;
    const int ri = ridx[w];
    const f2 rp = *(const f2*)(prel + (size_t)ri * 128 + c);
    const h2 rph = {(half_t)(rp[0] * LOG2E), (half_t)(rp[1] * LOG2E)};
    const float init = (lane == 0) ? -ESHIFT2 : 0.f;
    const int* __restrict__ hp = hA + (size_t)w * 16;
    const int* __restrict__ tp = tA + (size_t)w * 16;
    const char* __restrict__ pb = (const char*)pattr;
    const unsigned cb = (unsigned)lane << 2;

    f2 oh = {0.f, 0.f}, ot = {0.f, 0.f};
    float sh = 0.f, st = 0.f;

    auto ld = [&](int idx) -> h2 {
        return *(const h2*)(pb + (((unsigned)idx << 8) + cb));
    };

    h2 bh[2][4], bt[2][4];
#pragma unroll
    for (int q = 0; q < 4; ++q) {
        bh[0][q] = ld(hp[q]);
        bt[0][q] = ld(tp[q]);
    }
#pragma unroll
    for (int b = 0; b < 4; ++b) {
        const int cur = b & 1, nxt = cur ^ 1;
        if (b < 3) {
#pragma unroll
            for (int q = 0; q < 4; ++q) {
                bh[nxt][q] = ld(hp[4 * (b + 1) + q]);
                bt[nxt][q] = ld(tp[4 * (b + 1) + q]);
            }
        }
        float pph[4], ppt[4];
#pragma unroll
        for (int q = 0; q < 4; ++q) {
            pph[q] = __builtin_amdgcn_fdot2(rph, bh[cur][q], init, false);
            ppt[q] = __builtin_amdgcn_fdot2(rph, bt[cur][q], init, false);
        }
        float Sh[4], St[4];
#pragma unroll
        for (int q = 0; q < 4; ++q) {
            Sh[q] = wave_red_bcast(pph[q]);
            St[q] = wave_red_bcast(ppt[q]);
        }
#pragma unroll
        for (int q = 0; q < 4; ++q) {
            float wh = EXP2(Sh[q]);
            float wt = EXP2(St[q]);
            sh += wh; st += wt;
            oh[0] = fmaf(wh, (float)bh[cur][q][0], oh[0]);
            oh[1] = fmaf(wh, (float)bh[cur][q][1], oh[1]);
            ot[0] = fmaf(wt, (float)bt[cur][q][0], ot[0]);
            ot[1] = fmaf(wt, (float)bt[cur][q][1], ot[1]);
        }
    }
    float invh = 1.f / sh, invt = 1.f / st;
    h2 hv = {(half_t)(oh[0] * invh + ot[0] * invt),
             (half_t)(oh[1] * invh + ot[1] * invt)};
    *(h2*)(s_emb16 + (size_t)w * 128 + c) = hv;
}

// ================================================================ fused dispatch kernels (r17 schedule)
// L1: attr-table MFMA projection (blocks FIRST — compute-critical)  ∥  CSR count+rank
__global__ __launch_bounds__(256) void k_attr_count(const float* __restrict__ attr, int NA,
                                                    const float* __restrict__ W,
                                                    const float* __restrict__ bias,
                                                    half_t* __restrict__ out16, int MB,
                                                    const int* __restrict__ ei, int E, int N,
                                                    int* __restrict__ cnt,
                                                    int* __restrict__ rank) {
    __shared__ alignas(16) char smem[128 * 136 * 2];
    int b = blockIdx.x;
    if (b < MB) gemm_mfma_body<float>(b, attr, NA, W, DE, 0, bias, nullptr, nullptr,
                                      nullptr, nullptr, nullptr, nullptr, out16, smem);
    else count_body(b - MB, ei, E, N, cnt, rank);
}

// L2: rel-table GEMMs (both)  ∥  CSR scan
__global__ __launch_bounds__(256) void k_rel_scan(const float* __restrict__ in, int rows,
                                                  const float* __restrict__ W1,
                                                  const float* __restrict__ b1,
                                                  float* __restrict__ out1,
                                                  const float* __restrict__ W2,
                                                  float* __restrict__ out2, int RB,
                                                  const int* __restrict__ cnt, int n,
                                                  int* __restrict__ indptr) {
    __shared__ alignas(16) char smem[128 * 128 * 4];  // rel Wt (64KB); scan uses first 20B
    int b = blockIdx.x;
    if (b < 2 * RB) rel_body(b % RB, b / RB, in, rows, W1, b1, out1, W2, out2, smem);
    else scan_body(cnt, n, indptr, smem);
}

// L3: entity attention (blocks FIRST — latency-critical)  ∥  atomic-free CSR fill
__global__ __launch_bounds__(256) void k_entity_fill(const int* __restrict__ hA,
                                                     const int* __restrict__ tA,
                                                     const int* __restrict__ ridx,
                                                     const half_t* __restrict__ pattr,
                                                     const float* __restrict__ prel,
                                                     half_t* __restrict__ s_emb16, int N, int EB,
                                                     const int* __restrict__ ei, int E,
                                                     const int* __restrict__ indptr,
                                                     const int* __restrict__ rank,
                                                     int* __restrict__ adj) {
    int b = blockIdx.x;
    if (b < EB) entity_body(b, hA, tA, ridx, pattr, prel, s_emb16, N);
    else fill_body(b - EB, ei, E, N, indptr, rank, adj);
}

// standalone MFMA GEMM (gat layers)
__global__ __launch_bounds__(256) void k_gemm_mfma_h(const half_t* __restrict__ A, int rows,
                                                     const float* __restrict__ W, int ldw, int wcol0,
                                                     const float* __restrict__ bias,
                                                     const float* __restrict__ addtab,
                                                     const int* __restrict__ addidx,
                                                     const float* __restrict__ avs,
                                                     const float* __restrict__ avd,
                                                     float* __restrict__ als,
                                                     float* __restrict__ ald,
                                                     half_t* __restrict__ out16) {
    __shared__ alignas(16) char smem[128 * 136 * 2];
    gemm_mfma_body<half_t>(blockIdx.x, A, rows, W, ldw, wcol0, bias, addtab, addidx,
                           avs, avd, als, ald, out16, smem);
}

// ---------------------------------------------------------------- GAT aggregate (CSR)
// TWO nodes per wave (halves), lane owns 4 cols. DATA double-buffer: two 8-edge
// batches (A/B); invariant "while consuming one batch, the other is in flight"
// -> ~16 outstanding gathers during consumption (r12 only prefetched indices).
// als/ald pre-scaled by log2(e) -> exp2. adj padded +16; idx clamped vs garbage.
__global__ __launch_bounds__(256) void k_aggregate(const int* __restrict__ indptr,
                                                   const int* __restrict__ adj,
                                                   const half_t* __restrict__ hsrc,
                                                   const float* __restrict__ als,
                                                   const float* __restrict__ ald,
                                                   const float* __restrict__ bias,
                                                   float* __restrict__ out,
                                                   half_t* __restrict__ out16, int N) {
    const int tid = threadIdx.x;
    const int wv = (blockIdx.x * 256 + tid) >> 6;
    const int nodeA = wv * 2;
    if (nodeA >= N) return;
    const int lane = tid & 63;
    const int node = min(nodeA + (lane >> 5), N - 1);
    const int sl = lane & 31;
    const int c = sl * 4;

    const int beg = indptr[node];
    const int deg = indptr[node + 1] - beg;   // >= 1 (self-loop)
    const float adn = ald[node];              // pre-scaled by log2(e)
    const char* __restrict__ hb = (const char*)hsrc;
    const unsigned cb = (unsigned)sl << 3;

    float acc[4] = {0.f, 0.f, 0.f, 0.f};
    float exsum = 0.f;

    int   iA[8], iB[8];
    float aA[8], aB[8];
    h4v   vA[8], vB[8];

#define LD_CLAMP(dst, off)                                                    \
    _Pragma("unroll")                                                         \
    for (int q = 0; q < 8; ++q) {                                             \
        int t_ = adj[beg + (off) + q];                                        \
        dst[q] = ((unsigned)t_ < (unsigned)N) ? t_ : 0;                       \
    }
#define ISSUE(idx, al, hv)                                                    \
    _Pragma("unroll")                                                         \
    for (int q = 0; q < 8; ++q) al[q] = als[idx[q]];                          \
    _Pragma("unroll")                                                         \
    for (int q = 0; q < 8; ++q)                                               \
        hv[q] = *(const h4v*)(hb + (((unsigned)idx[q] << 8) + cb));
#define CONSUME(base, al, hv)                                                 \
    _Pragma("unroll")                                                         \
    for (int q = 0; q < 8; ++q) {                                             \
        bool ok_ = ((base) + q) < deg;                                        \
        float e_ = al[q] + adn;                                               \
        e_ = fmaxf(e_, NEG_SLOPE * e_);                                       \
        float ex_ = ok_ ? EXP2(e_ - ESHIFT_AGG) : 0.f;                        \
        exsum += ex_;                                                         \
        _Pragma("unroll")                                                     \
        for (int j = 0; j < 4; ++j) acc[j] = fmaf(ex_, (float)hv[q][j], acc[j]); \
    }

    // prologue: both batches issued (adj +16 pad covers reads)
    LD_CLAMP(iA, 0); ISSUE(iA, aA, vA);
    LD_CLAMP(iB, 8); ISSUE(iB, aB, vB);

    int j0 = 0;
#pragma unroll 1
    for (; j0 + 16 < deg; j0 += 16) {
        CONSUME(j0, aA, vA);                       // B in flight
        LD_CLAMP(iA, j0 + 16); ISSUE(iA, aA, vA);  // A' in flight
        CONSUME(j0 + 8, aB, vB);                   // A' in flight
        if (j0 + 24 < deg) { LD_CLAMP(iB, j0 + 24); ISSUE(iB, aB, vB); }
    }
    CONSUME(j0, aA, vA);
    if (j0 + 8 < deg) { CONSUME(j0 + 8, aB, vB); }

#undef LD_CLAMP
#undef ISSUE
#undef CONSUME

    float inv = 1.f / exsum;
    if (out) {
        f4 o;
#pragma unroll
        for (int j = 0; j < 4; ++j) o[j] = fmaf(acc[j], inv, bias[c + j]);
        *(f4*)(out + (size_t)node * 128 + c) = o;
    } else {
        h4v o;
#pragma unroll
        for (int j = 0; j < 4; ++j) o[j] = (half_t)fmaf(acc[j], inv, bias[c + j]);
        *(h4v*)(out16 + (size_t)node * 128 + c) = o;
    }
}

// ---------------------------------------------------------------- launch (r17 schedule)
extern "C" void kernel_launch(void* const* d_in, const int* in_sizes, int n_in,
                              void* d_out, int out_size, void* d_ws, size_t ws_size,
                              hipStream_t stream) {
    const int*   hA   = (const int*)d_in[0];
    const int*   tA   = (const int*)d_in[1];
    const int*   rix  = (const int*)d_in[2];
    const int*   ei   = (const int*)d_in[3];
    const float* attr_table = (const float*)d_in[4];
    const float* rel_table  = (const float*)d_in[5];
    const float* femb_w = (const float*)d_in[6];
    const float* femb_b = (const float*)d_in[7];
    const float* g1w  = (const float*)d_in[8];
    const float* g1as = (const float*)d_in[9];
    const float* g1ad = (const float*)d_in[10];
    const float* g1b  = (const float*)d_in[11];
    const float* g2w  = (const float*)d_in[12];
    const float* g2as = (const float*)d_in[13];
    const float* g2ad = (const float*)d_in[14];
    const float* g2b  = (const float*)d_in[15];

    const int N  = in_sizes[2];
    const int E  = in_sizes[3] / 2;
    const int NA = in_sizes[4] / DE;
    const int NR = in_sizes[5] / DE;
    const int EN = E + N;

    char* p = (char*)d_ws;
    auto alloc = [&](size_t bytes) -> char* {
        char* q = p;
        p += (bytes + 255) & ~(size_t)255;
        return q;
    };
    half_t* proj16 = (half_t*)alloc((size_t)NA * DE * 2);
    half_t* s16    = (half_t*)alloc((size_t)N * DE * 2);
    half_t* h16    = (half_t*)alloc((size_t)N * DE * 2);
    half_t* x116   = (half_t*)alloc((size_t)N * DE * 2);
    float* prel    = (float*)alloc((size_t)NR * DE * 4);
    float* rel2    = (float*)alloc((size_t)NR * DE * 4);
    float* alps    = (float*)alloc((size_t)N * 4);
    float* alpd    = (float*)alloc((size_t)N * 4);
    int*   indptr  = (int*)alloc((size_t)(N + 1) * 4);
    int*   cnt     = (int*)alloc((size_t)N * 4);
    int*   rank    = (int*)alloc((size_t)EN * 4);
    int*   adj     = (int*)alloc((size_t)(EN + 16) * 4);  // +16 pad for batch over-read

    dim3 b256(256);
    const int CB = (EN + 255) / 256;         // count/fill blocks
    const int MB = (NA + 63) / 64;           // attr mfma blocks
    const int RB = (NR + 31) / 32;           // rel gemm blocks (per W)
    const int GB = (N + 63) / 64;            // gat gemm blocks
    const int EB = (N + 3) / 4;              // entity blocks

    hipMemsetAsync(cnt, 0, (size_t)N * 4, stream);

    // L1: attr MFMA (first) ∥ CSR count (+rank record)
    k_attr_count<<<dim3(MB + CB), b256, 0, stream>>>(attr_table, NA, femb_w, femb_b,
                                                     proj16, MB, ei, E, N, cnt, rank);

    // L2: rel-table GEMMs ∥ CSR scan
    k_rel_scan<<<dim3(2 * RB + 1), b256, 0, stream>>>(rel_table, NR, femb_w, femb_b, prel,
                                                      g1w, rel2, RB, cnt, N, indptr);

    // L3: entity (first) ∥ atomic-free fill
    k_entity_fill<<<dim3(EB + CB), b256, 0, stream>>>(hA, tA, rix, proj16, prel, s16, N, EB,
                                                      ei, E, indptr, rank, adj);

    // L4: GAT-1 GEMM standalone (alpha fused, pre-scaled; h fp16)
    k_gemm_mfma_h<<<dim3(GB), b256, 0, stream>>>(s16, N,
        g1w, 2 * DE, 0, nullptr, rel2, rix, g1as, g1ad, alps, alpd, h16);

    k_aggregate<<<dim3((N + 7) / 8), b256, 0, stream>>>(indptr, adj, h16, alps, alpd, g1b,
                                                        nullptr, x116, N);

    // GAT layer 2
    k_gemm_mfma_h<<<dim3(GB), b256, 0, stream>>>(x116, N,
        g2w, DE, 0, nullptr, nullptr, nullptr, g2as, g2ad, alps, alpd, h16);
    k_aggregate<<<dim3((N + 7) / 8), b256, 0, stream>>>(indptr, adj, h16, alps, alpd, g2b,
                                                        (float*)d_out, nullptr, N);
}

// Round 20
// 263.099 us; speedup vs baseline: 1.0397x; 1.0397x over previous
//
#include <hip/hip_runtime.h>
#include <math.h>

#define DE 128
#define NEG_SLOPE 0.2f
#define LOG2E 1.4426950408889634f
#define ESHIFT2 57.707801635559926f      /* 40 * log2(e)  (entity) */
#define ESHIFT_AGG 28.853900817779268f   /* 20 * log2(e)  (aggregate) */
#define EXP2(x) __builtin_amdgcn_exp2f(x)  /* raw v_exp_f32; inputs bounded */

typedef __attribute__((ext_vector_type(4))) float f4;
typedef __attribute__((ext_vector_type(2))) float f2;
typedef _Float16 half_t;
typedef __attribute__((ext_vector_type(2))) _Float16 h2;
typedef __attribute__((ext_vector_type(4))) _Float16 h4v;
typedef __attribute__((ext_vector_type(8))) _Float16 h8;

// Wave64 sum-reduce on the VALU only (DPP adds + readlane), zero LDS-pipe ops.
__device__ __forceinline__ float wave_red_bcast(float x) {
    union fi { float f; int i; };
    fi a; a.f = x;
    fi t;
    t.i = __builtin_amdgcn_update_dpp(0, a.i, 0x111, 0xf, 0xf, true); a.f += t.f; // row_shr:1
    t.i = __builtin_amdgcn_update_dpp(0, a.i, 0x112, 0xf, 0xf, true); a.f += t.f; // row_shr:2
    t.i = __builtin_amdgcn_update_dpp(0, a.i, 0x114, 0xf, 0xf, true); a.f += t.f; // row_shr:4
    t.i = __builtin_amdgcn_update_dpp(0, a.i, 0x118, 0xf, 0xf, true); a.f += t.f; // row_shr:8
    t.i = __builtin_amdgcn_update_dpp(0, a.i, 0x142, 0xa, 0xf, true); a.f += t.f; // row_bcast:15
    t.i = __builtin_amdgcn_update_dpp(0, a.i, 0x143, 0xc, 0xf, true); a.f += t.f; // row_bcast:31
    fi r; r.i = __builtin_amdgcn_readlane(a.i, 63);
    return r.f;
}

// All-reduce within each 16-lane DPP row (lane gets its row's sum). 4 DPP adds.
__device__ __forceinline__ float row16_allred(float x) {
    union fi { float f; int i; };
    fi a; a.f = x;
    fi t;
    t.i = __builtin_amdgcn_update_dpp(0, a.i, 0x121, 0xf, 0xf, true); a.f += t.f; // row_ror:1
    t.i = __builtin_amdgcn_update_dpp(0, a.i, 0x122, 0xf, 0xf, true); a.f += t.f; // row_ror:2
    t.i = __builtin_amdgcn_update_dpp(0, a.i, 0x124, 0xf, 0xf, true); a.f += t.f; // row_ror:4
    t.i = __builtin_amdgcn_update_dpp(0, a.i, 0x128, 0xf, 0xf, true); a.f += t.f; // row_ror:8
    return a.f;
}

// ================================================================ CSR bodies
// count ALSO records each edge's rank among same-dst edges (atomic return value)
// -> fill needs NO atomics at all.
__device__ __forceinline__ void count_body(int bid, const int* __restrict__ ei, int E, int N,
                                           int* __restrict__ cnt, int* __restrict__ rank) {
    int e = bid * 256 + threadIdx.x;
    int total = E + N;
    if (e >= total) return;
    int dst = (e < E) ? ei[E + e] : (e - E);
    rank[e] = atomicAdd(&cnt[dst], 1);  // rank write is coalesced (indexed by e)
}

// 256-thread block scan, 4 items/thread per 1024-tile. smem: >= 5 ints.
__device__ void scan_body(const int* __restrict__ cnt, int n, int* __restrict__ indptr,
                          char* smem) {
    int* wsum = (int*)smem;       // [4]
    int* btot = (int*)smem + 4;
    const int tid = threadIdx.x, lane = tid & 63, w = tid >> 6;
    int carry = 0;
    for (int base = 0; base < n; base += 1024) {
        int i0 = base + tid * 4;
        int4 v = {0, 0, 0, 0};
        if (i0 + 3 < n) v = *(const int4*)(cnt + i0);
        else {
            if (i0 < n)     v.x = cnt[i0];
            if (i0 + 1 < n) v.y = cnt[i0 + 1];
            if (i0 + 2 < n) v.z = cnt[i0 + 2];
        }
        int s = v.x + v.y + v.z + v.w;
        int x = s;
#pragma unroll
        for (int off = 1; off < 64; off <<= 1) {
            int t = __shfl_up(x, off, 64);
            if (lane >= off) x += t;
        }
        if (lane == 63) wsum[w] = x;
        __syncthreads();
        if (tid == 0) {
            int acc = 0;
#pragma unroll
            for (int k = 0; k < 4; ++k) { int t = wsum[k]; wsum[k] = acc; acc += t; }
            *btot = acc;
        }
        __syncthreads();
        int excl = carry + wsum[w] + (x - s);
        if (i0 < n)     indptr[i0]     = excl;
        if (i0 + 1 < n) indptr[i0 + 1] = excl + v.x;
        if (i0 + 2 < n) indptr[i0 + 2] = excl + v.x + v.y;
        if (i0 + 3 < n) indptr[i0 + 3] = excl + v.x + v.y + v.z;
        carry += *btot;
        __syncthreads();
    }
    if (tid == 0) indptr[n] = carry;
}

// atomic-free fill: pos = indptr[dst] + rank[e]
__device__ __forceinline__ void fill_body(int bid, const int* __restrict__ ei, int E, int N,
                                          const int* __restrict__ indptr,
                                          const int* __restrict__ rank,
                                          int* __restrict__ adj) {
    int e = bid * 256 + threadIdx.x;
    int total = E + N;
    if (e >= total) return;
    int src, dst;
    if (e < E) { src = ei[e]; dst = ei[E + e]; }
    else       { src = dst = e - E; }
    adj[indptr[dst] + rank[e]] = src;
}

// ================================================================ rel-table GEMM body (500 rows)
__device__ void rel_body(int bx, int sel, const float* __restrict__ in, int rows,
                         const float* __restrict__ W1, const float* __restrict__ bias1,
                         float* __restrict__ out1, const float* __restrict__ W2,
                         float* __restrict__ out2, char* smem) {
    const float* W; int ldw, wcol0; const float* bias; float* out;
    if (sel == 0) { W = W1; ldw = DE;     wcol0 = 0;  bias = bias1;   out = out1; }
    else          { W = W2; ldw = 2 * DE; wcol0 = DE; bias = nullptr; out = out2; }

    float* Wt = (float*)smem;  // [128*128]
    const int tid = threadIdx.x;
#pragma unroll
    for (int it = 0; it < 16; ++it) {
        int idx = it * 256 + tid;
        int c = idx & 127, k4 = idx >> 7;
        f4 wv = *(const f4*)(W + (size_t)c * ldw + wcol0 + k4 * 4);
#pragma unroll
        for (int j = 0; j < 4; ++j) Wt[(4 * k4 + j) * 128 + c] = wv[j];
    }
    __syncthreads();

    const int RPT = 2;
    const int cgrp = tid & 15, rgrp = tid >> 4;
    const int c0 = cgrp * 4;
    const int row0 = bx * (16 * RPT) + rgrp * RPT;

    const float* rowp[RPT];
#pragma unroll
    for (int i = 0; i < RPT; ++i)
        rowp[i] = in + (size_t)min(row0 + i, rows - 1) * 128;

    float acc[RPT][8];
#pragma unroll
    for (int i = 0; i < RPT; ++i)
#pragma unroll
        for (int j = 0; j < 8; ++j) acc[i][j] = 0.f;

#pragma unroll 1
    for (int k = 0; k < 128; k += 4) {
        f4 a[RPT];
#pragma unroll
        for (int i = 0; i < RPT; ++i) a[i] = *(const f4*)(rowp[i] + k);
#pragma unroll
        for (int kk = 0; kk < 4; ++kk) {
            f4 b0 = *(const f4*)&Wt[(k + kk) * 128 + c0];
            f4 b1 = *(const f4*)&Wt[(k + kk) * 128 + c0 + 64];
#pragma unroll
            for (int i = 0; i < RPT; ++i) {
                float av = a[i][kk];
#pragma unroll
                for (int j = 0; j < 4; ++j) {
                    acc[i][j]     = fmaf(av, b0[j], acc[i][j]);
                    acc[i][j + 4] = fmaf(av, b1[j], acc[i][j + 4]);
                }
            }
        }
    }
    f4 bi0 = {0.f,0.f,0.f,0.f}, bi1 = {0.f,0.f,0.f,0.f};
    if (bias) { bi0 = *(const f4*)(bias + c0); bi1 = *(const f4*)(bias + c0 + 64); }
#pragma unroll
    for (int i = 0; i < RPT; ++i) {
        int r = row0 + i;
        if (r < rows) {
            f4 v0, v1;
#pragma unroll
            for (int j = 0; j < 4; ++j) { v0[j] = acc[i][j] + bi0[j]; v1[j] = acc[i][j+4] + bi1[j]; }
            *(f4*)(out + (size_t)r * 128 + c0) = v0;
            *(f4*)(out + (size_t)r * 128 + c0 + 64) = v1;
        }
    }
}

// ================================================================ MFMA GEMM body (fp16 in, f32 acc)
// als/ald stored PRE-SCALED by log2(e). smem: 128*136*2 bytes.
template <typename AT>
__device__ void gemm_mfma_body(int bid, const AT* __restrict__ A, int rows,
                               const float* __restrict__ W, int ldw, int wcol0,
                               const float* __restrict__ bias,
                               const float* __restrict__ addtab,
                               const int* __restrict__ addidx,
                               const float* __restrict__ avs,
                               const float* __restrict__ avd,
                               float* __restrict__ als,
                               float* __restrict__ ald,
                               half_t* __restrict__ out16, char* smem) {
    half_t* Wl = (half_t*)smem;
    float*  Dl = (float*)smem;

    const int tid = threadIdx.x;
    const int row0 = bid * 64;

    for (int i = tid * 4; i < 128 * 128; i += 1024) {
        int c = i >> 7, k = i & 127;
        f4 wv = *(const f4*)(W + (size_t)c * ldw + wcol0 + k);
        h4v hv = {(half_t)wv[0], (half_t)wv[1], (half_t)wv[2], (half_t)wv[3]};
        *(h4v*)(Wl + c * 136 + k) = hv;
    }
    __syncthreads();

    const int wv_id = tid >> 6, l = tid & 63, lr = l & 15, lk = l >> 4;
    const int r_a = min(row0 + wv_id * 16 + lr, rows - 1);

    h8 af[4];
#pragma unroll
    for (int ks = 0; ks < 4; ++ks) {
        if constexpr (sizeof(AT) == 4) {
            f4 a0 = *(const f4*)(A + (size_t)r_a * 128 + ks * 32 + lk * 8);
            f4 a1 = *(const f4*)(A + (size_t)r_a * 128 + ks * 32 + lk * 8 + 4);
            h8 v = {(half_t)a0[0], (half_t)a0[1], (half_t)a0[2], (half_t)a0[3],
                    (half_t)a1[0], (half_t)a1[1], (half_t)a1[2], (half_t)a1[3]};
            af[ks] = v;
        } else {
            af[ks] = *(const h8*)(A + (size_t)r_a * 128 + ks * 32 + lk * 8);
        }
    }

    f4 acc[8];
#pragma unroll
    for (int t = 0; t < 8; ++t) acc[t] = (f4){0.f, 0.f, 0.f, 0.f};
#pragma unroll
    for (int ks = 0; ks < 4; ++ks) {
#pragma unroll
        for (int t = 0; t < 8; ++t) {
            h8 bf = *(const h8*)(Wl + (t * 16 + lr) * 136 + ks * 32 + lk * 8);
            acc[t] = __builtin_amdgcn_mfma_f32_16x16x32_f16(af[ks], bf, acc[t], 0, 0, 0);
        }
    }
    __syncthreads();

#pragma unroll
    for (int t = 0; t < 8; ++t)
#pragma unroll
        for (int q = 0; q < 4; ++q)
            Dl[(wv_id * 16 + lk * 4 + q) * 132 + t * 16 + lr] = acc[t][q];
    __syncthreads();

    const int cl = (tid & 15) * 8;
    f4 bi0 = {0.f,0.f,0.f,0.f}, bi1 = bi0;
    if (bias) { bi0 = *(const f4*)(bias + cl); bi1 = *(const f4*)(bias + cl + 4); }
    f4 as0 = {0.f,0.f,0.f,0.f}, as1 = as0, ad0 = as0, ad1 = as0;
    if (als) {
        as0 = *(const f4*)(avs + cl) * LOG2E; as1 = *(const f4*)(avs + cl + 4) * LOG2E;
        ad0 = *(const f4*)(avd + cl) * LOG2E; ad1 = *(const f4*)(avd + cl + 4) * LOG2E;
    }
#pragma unroll
    for (int pass = 0; pass < 4; ++pass) {
        int lrow = pass * 16 + (tid >> 4);
        int r = row0 + lrow;
        bool ok = r < rows;
        f4 v0 = *(const f4*)(Dl + lrow * 132 + cl);
        f4 v1 = *(const f4*)(Dl + lrow * 132 + cl + 4);
        v0 += bi0; v1 += bi1;
        if (addtab) {
            int ri = addidx[min(r, rows - 1)];
            v0 += *(const f4*)(addtab + (size_t)ri * 128 + cl);
            v1 += *(const f4*)(addtab + (size_t)ri * 128 + cl + 4);
        }
        if (als) {
            float ps = 0.f, pd = 0.f;
#pragma unroll
            for (int j = 0; j < 4; ++j) {
                ps += v0[j] * as0[j] + v1[j] * as1[j];
                pd += v0[j] * ad0[j] + v1[j] * ad1[j];
            }
            ps = row16_allred(ps);
            pd = row16_allred(pd);
            if ((tid & 15) == 0 && ok) { als[r] = ps; ald[r] = pd; }
        }
        if (ok) {
            h8 o = {(half_t)v0[0], (half_t)v0[1], (half_t)v0[2], (half_t)v0[3],
                    (half_t)v1[0], (half_t)v1[1], (half_t)v1[2], (half_t)v1[3]};
            *(h8*)(out16 + (size_t)r * 128 + cl) = o;
        }
    }
}

// ================================================================ entity body (FROZEN structure)
__device__ void entity_body(int bid, const int* __restrict__ hA,
                            const int* __restrict__ tA,
                            const int* __restrict__ ridx,
                            const half_t* __restrict__ pattr,
                            const float* __restrict__ prel,
                            half_t* __restrict__ s_emb16, int N) {
    int w = (bid * 256 + (int)threadIdx.x) >> 6;
    if (w >= N) return;
    w = __builtin_amdgcn_readfirstlane(w);
    const int lane = threadIdx.x & 63;
    const int c = lane * 2;
    const int ri = ridx[w];
    const f2 rp = *(const f2*)(prel + (size_t)ri * 128 + c);
    const h2 rph = {(half_t)(rp[0] * LOG2E), (half_t)(rp[1] * LOG2E)};
    const float init = (lane == 0) ? -ESHIFT2 : 0.f;
    const int* __restrict__ hp = hA + (size_t)w * 16;
    const int* __restrict__ tp = tA + (size_t)w * 16;
    const char* __restrict__ pb = (const char*)pattr;
    const unsigned cb = (unsigned)lane << 2;

    f2 oh = {0.f, 0.f}, ot = {0.f, 0.f};
    float sh = 0.f, st = 0.f;

    auto ld = [&](int idx) -> h2 {
        return *(const h2*)(pb + (((unsigned)idx << 8) + cb));
    };

    h2 bh[2][4], bt[2][4];
#pragma unroll
    for (int q = 0; q < 4; ++q) {
        bh[0][q] = ld(hp[q]);
        bt[0][q] = ld(tp[q]);
    }
#pragma unroll
    for (int b = 0; b < 4; ++b) {
        const int cur = b & 1, nxt = cur ^ 1;
        if (b < 3) {
#pragma unroll
            for (int q = 0; q < 4; ++q) {
                bh[nxt][q] = ld(hp[4 * (b + 1) + q]);
                bt[nxt][q] = ld(tp[4 * (b + 1) + q]);
            }
        }
        float pph[4], ppt[4];
#pragma unroll
        for (int q = 0; q < 4; ++q) {
            pph[q] = __builtin_amdgcn_fdot2(rph, bh[cur][q], init, false);
            ppt[q] = __builtin_amdgcn_fdot2(rph, bt[cur][q], init, false);
        }
        float Sh[4], St[4];
#pragma unroll
        for (int q = 0; q < 4; ++q) {
            Sh[q] = wave_red_bcast(pph[q]);
            St[q] = wave_red_bcast(ppt[q]);
        }
#pragma unroll
        for (int q = 0; q < 4; ++q) {
            float wh = EXP2(Sh[q]);
            float wt = EXP2(St[q]);
            sh += wh; st += wt;
            oh[0] = fmaf(wh, (float)bh[cur][q][0], oh[0]);
            oh[1] = fmaf(wh, (float)bh[cur][q][1], oh[1]);
            ot[0] = fmaf(wt, (float)bt[cur][q][0], ot[0]);
            ot[1] = fmaf(wt, (float)bt[cur][q][1], ot[1]);
        }
    }
    float invh = 1.f / sh, invt = 1.f / st;
    h2 hv = {(half_t)(oh[0] * invh + ot[0] * invt),
             (half_t)(oh[1] * invh + ot[1] * invt)};
    *(h2*)(s_emb16 + (size_t)w * 128 + c) = hv;
}

// ================================================================ fused dispatch kernels
// L1: attr-table MFMA projection (blocks FIRST — compute-critical)  ∥  CSR count+rank
__global__ __launch_bounds__(256) void k_attr_count(const float* __restrict__ attr, int NA,
                                                    const float* __restrict__ W,
                                                    const float* __restrict__ bias,
                                                    half_t* __restrict__ out16, int MB,
                                                    const int* __restrict__ ei, int E, int N,
                                                    int* __restrict__ cnt,
                                                    int* __restrict__ rank) {
    __shared__ alignas(16) char smem[128 * 136 * 2];
    int b = blockIdx.x;
    if (b < MB) gemm_mfma_body<float>(b, attr, NA, W, DE, 0, bias, nullptr, nullptr,
                                      nullptr, nullptr, nullptr, nullptr, out16, smem);
    else count_body(b - MB, ei, E, N, cnt, rank);
}

// L2: rel-table GEMMs (both)  ∥  CSR scan
__global__ __launch_bounds__(256) void k_rel_scan(const float* __restrict__ in, int rows,
                                                  const float* __restrict__ W1,
                                                  const float* __restrict__ b1,
                                                  float* __restrict__ out1,
                                                  const float* __restrict__ W2,
                                                  float* __restrict__ out2, int RB,
                                                  const int* __restrict__ cnt, int n,
                                                  int* __restrict__ indptr) {
    __shared__ alignas(16) char smem[128 * 128 * 4];  // rel Wt (64KB); scan uses first 20B
    int b = blockIdx.x;
    if (b < 2 * RB) rel_body(b % RB, b / RB, in, rows, W1, b1, out1, W2, out2, smem);
    else scan_body(cnt, n, indptr, smem);
}

// entity standalone (latency-critical; keep CUs to itself)
__global__ __launch_bounds__(256) void k_entity(const int* __restrict__ hA,
                                                const int* __restrict__ tA,
                                                const int* __restrict__ ridx,
                                                const half_t* __restrict__ pattr,
                                                const float* __restrict__ prel,
                                                half_t* __restrict__ s_emb16, int N) {
    entity_body(blockIdx.x, hA, tA, ridx, pattr, prel, s_emb16, N);
}

// L3: entity attention (blocks FIRST — latency-critical)  ∥  atomic-free CSR fill
__global__ __launch_bounds__(256) void k_entity_fill(const int* __restrict__ hA,
                                                     const int* __restrict__ tA,
                                                     const int* __restrict__ ridx,
                                                     const half_t* __restrict__ pattr,
                                                     const float* __restrict__ prel,
                                                     half_t* __restrict__ s_emb16, int N, int EB,
                                                     const int* __restrict__ ei, int E,
                                                     const int* __restrict__ indptr,
                                                     const int* __restrict__ rank,
                                                     int* __restrict__ adj) {
    int b = blockIdx.x;
    if (b < EB) entity_body(b, hA, tA, ridx, pattr, prel, s_emb16, N);
    else fill_body(b - EB, ei, E, N, indptr, rank, adj);
}

// standalone MFMA GEMM (gat layers)
__global__ __launch_bounds__(256) void k_gemm_mfma_h(const half_t* __restrict__ A, int rows,
                                                     const float* __restrict__ W, int ldw, int wcol0,
                                                     const float* __restrict__ bias,
                                                     const float* __restrict__ addtab,
                                                     const int* __restrict__ addidx,
                                                     const float* __restrict__ avs,
                                                     const float* __restrict__ avd,
                                                     float* __restrict__ als,
                                                     float* __restrict__ ald,
                                                     half_t* __restrict__ out16) {
    __shared__ alignas(16) char smem[128 * 136 * 2];
    gemm_mfma_body<half_t>(blockIdx.x, A, rows, W, ldw, wcol0, bias, addtab, addidx,
                           avs, avd, als, ald, out16, smem);
}

// ---------------------------------------------------------------- GAT aggregate (CSR, r17 form — FROZEN)
__global__ __launch_bounds__(256) void k_aggregate(const int* __restrict__ indptr,
                                                   const int* __restrict__ adj,
                                                   const half_t* __restrict__ hsrc,
                                                   const float* __restrict__ als,
                                                   const float* __restrict__ ald,
                                                   const float* __restrict__ bias,
                                                   float* __restrict__ out,
                                                   half_t* __restrict__ out16, int N) {
    const int tid = threadIdx.x;
    const int wv = (blockIdx.x * 256 + tid) >> 6;
    const int nodeA = wv * 2;
    if (nodeA >= N) return;
    const int lane = tid & 63;
    const int node = min(nodeA + (lane >> 5), N - 1);
    const int sl = lane & 31;
    const int c = sl * 4;

    const int beg = indptr[node];
    const int deg = indptr[node + 1] - beg;   // >= 1 (self-loop)
    const float adn = ald[node];              // pre-scaled by log2(e)
    const char* __restrict__ hb = (const char*)hsrc;
    const unsigned cb = (unsigned)sl << 3;

    float acc[4] = {0.f, 0.f, 0.f, 0.f};
    float exsum = 0.f;

    int cur[8], nxt[8];
#pragma unroll
    for (int q = 0; q < 8; ++q) cur[q] = adj[beg + q];  // batch 0 (padded)

#pragma unroll 1
    for (int j0 = 0; j0 < deg; j0 += 8) {
        if (j0 + 8 < deg) {
#pragma unroll
            for (int q = 0; q < 8; ++q) nxt[q] = adj[beg + j0 + 8 + q];
        }
        int ss[8];
        float alv[8];
        h4v hv[8];
#pragma unroll
        for (int q = 0; q < 8; ++q)
            ss[q] = ((unsigned)cur[q] < (unsigned)N) ? cur[q] : 0;
#pragma unroll
        for (int q = 0; q < 8; ++q) alv[q] = als[ss[q]];
#pragma unroll
        for (int q = 0; q < 8; ++q)
            hv[q] = *(const h4v*)(hb + (((unsigned)ss[q] << 8) + cb));
#pragma unroll
        for (int q = 0; q < 8; ++q) {
            bool ok = (j0 + q) < deg;
            float e = alv[q] + adn;
            e = fmaxf(e, NEG_SLOPE * e);
            float ex = ok ? EXP2(e - ESHIFT_AGG) : 0.f;
            exsum += ex;
#pragma unroll
            for (int j = 0; j < 4; ++j) acc[j] = fmaf(ex, (float)hv[q][j], acc[j]);
        }
#pragma unroll
        for (int q = 0; q < 8; ++q) cur[q] = nxt[q];
    }

    float inv = 1.f / exsum;
    if (out) {
        f4 o;
#pragma unroll
        for (int j = 0; j < 4; ++j) o[j] = fmaf(acc[j], inv, bias[c + j]);
        *(f4*)(out + (size_t)node * 128 + c) = o;
    } else {
        h4v o;
#pragma unroll
        for (int j = 0; j < 4; ++j) o[j] = (half_t)fmaf(acc[j], inv, bias[c + j]);
        *(h4v*)(out16 + (size_t)node * 128 + c) = o;
    }
}

// ---------------------------------------------------------------- launch (r17 schedule)
extern "C" void kernel_launch(void* const* d_in, const int* in_sizes, int n_in,
                              void* d_out, int out_size, void* d_ws, size_t ws_size,
                              hipStream_t stream) {
    const int*   hA   = (const int*)d_in[0];
    const int*   tA   = (const int*)d_in[1];
    const int*   rix  = (const int*)d_in[2];
    const int*   ei   = (const int*)d_in[3];
    const float* attr_table = (const float*)d_in[4];
    const float* rel_table  = (const float*)d_in[5];
    const float* femb_w = (const float*)d_in[6];
    const float* femb_b = (const float*)d_in[7];
    const float* g1w  = (const float*)d_in[8];
    const float* g1as = (const float*)d_in[9];
    const float* g1ad = (const float*)d_in[10];
    const float* g1b  = (const float*)d_in[11];
    const float* g2w  = (const float*)d_in[12];
    const float* g2as = (const float*)d_in[13];
    const float* g2ad = (const float*)d_in[14];
    const float* g2b  = (const float*)d_in[15];

    const int N  = in_sizes[2];
    const int E  = in_sizes[3] / 2;
    const int NA = in_sizes[4] / DE;
    const int NR = in_sizes[5] / DE;
    const int EN = E + N;

    char* p = (char*)d_ws;
    auto alloc = [&](size_t bytes) -> char* {
        char* q = p;
        p += (bytes + 255) & ~(size_t)255;
        return q;
    };
    half_t* proj16 = (half_t*)alloc((size_t)NA * DE * 2);
    half_t* s16    = (half_t*)alloc((size_t)N * DE * 2);
    half_t* h16    = (half_t*)alloc((size_t)N * DE * 2);
    half_t* x116   = (half_t*)alloc((size_t)N * DE * 2);
    float* prel    = (float*)alloc((size_t)NR * DE * 4);
    float* rel2    = (float*)alloc((size_t)NR * DE * 4);
    float* alps    = (float*)alloc((size_t)N * 4);
    float* alpd    = (float*)alloc((size_t)N * 4);
    int*   indptr  = (int*)alloc((size_t)(N + 1) * 4);
    int*   cnt     = (int*)alloc((size_t)N * 4);
    int*   rank    = (int*)alloc((size_t)EN * 4);
    int*   adj     = (int*)alloc((size_t)(EN + 16) * 4);  // +16 pad for batch-8 over-read

    dim3 b256(256);
    const int CB = (EN + 255) / 256;         // count/fill blocks
    const int MB = (NA + 63) / 64;           // attr mfma blocks
    const int RB = (NR + 31) / 32;           // rel gemm blocks (per W)
    const int GB = (N + 63) / 64;            // gat gemm blocks
    const int EB = (N + 3) / 4;              // entity blocks

    hipMemsetAsync(cnt, 0, (size_t)N * 4, stream);

    // L1: attr MFMA (first) ∥ CSR count (+rank record)
    k_attr_count<<<dim3(MB + CB), b256, 0, stream>>>(attr_table, NA, femb_w, femb_b,
                                                     proj16, MB, ei, E, N, cnt, rank);

    // L2: rel-table GEMMs ∥ CSR scan
    k_rel_scan<<<dim3(2 * RB + 1), b256, 0, stream>>>(rel_table, NR, femb_w, femb_b, prel,
                                                      g1w, rel2, RB, cnt, N, indptr);

    // L3: entity (first) ∥ atomic-free fill
    k_entity_fill<<<dim3(EB + CB), b256, 0, stream>>>(hA, tA, rix, proj16, prel, s16, N, EB,
                                                      ei, E, indptr, rank, adj);

    // L4: GAT-1 GEMM standalone (alpha fused, pre-scaled; h fp16)
    k_gemm_mfma_h<<<dim3(GB), b256, 0, stream>>>(s16, N,
        g1w, 2 * DE, 0, nullptr, rel2, rix, g1as, g1ad, alps, alpd, h16);

    k_aggregate<<<dim3((N + 7) / 8), b256, 0, stream>>>(indptr, adj, h16, alps, alpd, g1b,
                                                        nullptr, x116, N);

    // GAT layer 2
    k_gemm_mfma_h<<<dim3(GB), b256, 0, stream>>>(x116, N,
        g2w, DE, 0, nullptr, nullptr, nullptr, g2as, g2ad, alps, alpd, h16);
    k_aggregate<<<dim3((N + 7) / 8), b256, 0, stream>>>(indptr, adj, h16, alps, alpd, g2b,
                                                        (float*)d_out, nullptr, N);
}

// Round 21
// 250.300 us; speedup vs baseline: 1.0929x; 1.0511x over previous
//
#include <hip/hip_runtime.h>
#include <math.h>

#define DE 128
#define NEG_SLOPE 0.2f
#define LOG2E 1.4426950408889634f
#define ESHIFT2 57.707801635559926f      /* 40 * log2(e)  (entity) */
#define ESHIFT_AGG 28.853900817779268f   /* 20 * log2(e)  (aggregate) */
#define EXP2(x) __builtin_amdgcn_exp2f(x)  /* raw v_exp_f32; inputs bounded */

typedef __attribute__((ext_vector_type(4))) float f4;
typedef __attribute__((ext_vector_type(2))) float f2;
typedef _Float16 half_t;
typedef __attribute__((ext_vector_type(2))) _Float16 h2;
typedef __attribute__((ext_vector_type(4))) _Float16 h4v;
typedef __attribute__((ext_vector_type(8))) _Float16 h8;

// Wave64 sum-reduce on the VALU only (DPP adds + readlane), zero LDS-pipe ops.
__device__ __forceinline__ float wave_red_bcast(float x) {
    union fi { float f; int i; };
    fi a; a.f = x;
    fi t;
    t.i = __builtin_amdgcn_update_dpp(0, a.i, 0x111, 0xf, 0xf, true); a.f += t.f; // row_shr:1
    t.i = __builtin_amdgcn_update_dpp(0, a.i, 0x112, 0xf, 0xf, true); a.f += t.f; // row_shr:2
    t.i = __builtin_amdgcn_update_dpp(0, a.i, 0x114, 0xf, 0xf, true); a.f += t.f; // row_shr:4
    t.i = __builtin_amdgcn_update_dpp(0, a.i, 0x118, 0xf, 0xf, true); a.f += t.f; // row_shr:8
    t.i = __builtin_amdgcn_update_dpp(0, a.i, 0x142, 0xa, 0xf, true); a.f += t.f; // row_bcast:15
    t.i = __builtin_amdgcn_update_dpp(0, a.i, 0x143, 0xc, 0xf, true); a.f += t.f; // row_bcast:31
    fi r; r.i = __builtin_amdgcn_readlane(a.i, 63);
    return r.f;
}

// All-reduce within each 16-lane DPP row (lane gets its row's sum). 4 DPP adds.
__device__ __forceinline__ float row16_allred(float x) {
    union fi { float f; int i; };
    fi a; a.f = x;
    fi t;
    t.i = __builtin_amdgcn_update_dpp(0, a.i, 0x121, 0xf, 0xf, true); a.f += t.f; // row_ror:1
    t.i = __builtin_amdgcn_update_dpp(0, a.i, 0x122, 0xf, 0xf, true); a.f += t.f; // row_ror:2
    t.i = __builtin_amdgcn_update_dpp(0, a.i, 0x124, 0xf, 0xf, true); a.f += t.f; // row_ror:4
    t.i = __builtin_amdgcn_update_dpp(0, a.i, 0x128, 0xf, 0xf, true); a.f += t.f; // row_ror:8
    return a.f;
}

// ================================================================ CSR bodies
// count ALSO records each edge's rank among same-dst edges (atomic return value)
// -> fill needs NO atomics at all.
__device__ __forceinline__ void count_body(int bid, const int* __restrict__ ei, int E, int N,
                                           int* __restrict__ cnt, int* __restrict__ rank) {
    int e = bid * 256 + threadIdx.x;
    int total = E + N;
    if (e >= total) return;
    int dst = (e < E) ? ei[E + e] : (e - E);
    rank[e] = atomicAdd(&cnt[dst], 1);  // rank write is coalesced (indexed by e)
}

// 256-thread block scan, 4 items/thread per 1024-tile. smem: >= 5 ints.
__device__ __forceinline__ void scan_body(const int* __restrict__ cnt, int n,
                                          int* __restrict__ indptr, char* smem) {
    int* wsum = (int*)smem;       // [4]
    int* btot = (int*)smem + 4;
    const int tid = threadIdx.x, lane = tid & 63, w = tid >> 6;
    int carry = 0;
    for (int base = 0; base < n; base += 1024) {
        int i0 = base + tid * 4;
        int4 v = {0, 0, 0, 0};
        if (i0 + 3 < n) v = *(const int4*)(cnt + i0);
        else {
            if (i0 < n)     v.x = cnt[i0];
            if (i0 + 1 < n) v.y = cnt[i0 + 1];
            if (i0 + 2 < n) v.z = cnt[i0 + 2];
        }
        int s = v.x + v.y + v.z + v.w;
        int x = s;
#pragma unroll
        for (int off = 1; off < 64; off <<= 1) {
            int t = __shfl_up(x, off, 64);
            if (lane >= off) x += t;
        }
        if (lane == 63) wsum[w] = x;
        __syncthreads();
        if (tid == 0) {
            int acc = 0;
#pragma unroll
            for (int k = 0; k < 4; ++k) { int t = wsum[k]; wsum[k] = acc; acc += t; }
            *btot = acc;
        }
        __syncthreads();
        int excl = carry + wsum[w] + (x - s);
        if (i0 < n)     indptr[i0]     = excl;
        if (i0 + 1 < n) indptr[i0 + 1] = excl + v.x;
        if (i0 + 2 < n) indptr[i0 + 2] = excl + v.x + v.y;
        if (i0 + 3 < n) indptr[i0 + 3] = excl + v.x + v.y + v.z;
        carry += *btot;
        __syncthreads();
    }
    if (tid == 0) indptr[n] = carry;
}

// atomic-free fill: pos = indptr[dst] + rank[e]
__device__ __forceinline__ void fill_body(int bid, const int* __restrict__ ei, int E, int N,
                                          const int* __restrict__ indptr,
                                          const int* __restrict__ rank,
                                          int* __restrict__ adj) {
    int e = bid * 256 + threadIdx.x;
    int total = E + N;
    if (e >= total) return;
    int src, dst;
    if (e < E) { src = ei[e]; dst = ei[E + e]; }
    else       { src = dst = e - E; }
    adj[indptr[dst] + rank[e]] = src;
}

// ================================================================ rel-table GEMM body (500 rows)
__device__ __forceinline__ void rel_body(int bx, int sel, const float* __restrict__ in, int rows,
                                         const float* __restrict__ W1, const float* __restrict__ bias1,
                                         float* __restrict__ out1, const float* __restrict__ W2,
                                         float* __restrict__ out2, char* smem) {
    const float* W; int ldw, wcol0; const float* bias; float* out;
    if (sel == 0) { W = W1; ldw = DE;     wcol0 = 0;  bias = bias1;   out = out1; }
    else          { W = W2; ldw = 2 * DE; wcol0 = DE; bias = nullptr; out = out2; }

    float* Wt = (float*)smem;  // [128*128]
    const int tid = threadIdx.x;
#pragma unroll
    for (int it = 0; it < 16; ++it) {
        int idx = it * 256 + tid;
        int c = idx & 127, k4 = idx >> 7;
        f4 wv = *(const f4*)(W + (size_t)c * ldw + wcol0 + k4 * 4);
#pragma unroll
        for (int j = 0; j < 4; ++j) Wt[(4 * k4 + j) * 128 + c] = wv[j];
    }
    __syncthreads();

    const int RPT = 2;
    const int cgrp = tid & 15, rgrp = tid >> 4;
    const int c0 = cgrp * 4;
    const int row0 = bx * (16 * RPT) + rgrp * RPT;

    const float* rowp[RPT];
#pragma unroll
    for (int i = 0; i < RPT; ++i)
        rowp[i] = in + (size_t)min(row0 + i, rows - 1) * 128;

    float acc[RPT][8];
#pragma unroll
    for (int i = 0; i < RPT; ++i)
#pragma unroll
        for (int j = 0; j < 8; ++j) acc[i][j] = 0.f;

#pragma unroll 1
    for (int k = 0; k < 128; k += 4) {
        f4 a[RPT];
#pragma unroll
        for (int i = 0; i < RPT; ++i) a[i] = *(const f4*)(rowp[i] + k);
#pragma unroll
        for (int kk = 0; kk < 4; ++kk) {
            f4 b0 = *(const f4*)&Wt[(k + kk) * 128 + c0];
            f4 b1 = *(const f4*)&Wt[(k + kk) * 128 + c0 + 64];
#pragma unroll
            for (int i = 0; i < RPT; ++i) {
                float av = a[i][kk];
#pragma unroll
                for (int j = 0; j < 4; ++j) {
                    acc[i][j]     = fmaf(av, b0[j], acc[i][j]);
                    acc[i][j + 4] = fmaf(av, b1[j], acc[i][j + 4]);
                }
            }
        }
    }
    f4 bi0 = {0.f,0.f,0.f,0.f}, bi1 = {0.f,0.f,0.f,0.f};
    if (bias) { bi0 = *(const f4*)(bias + c0); bi1 = *(const f4*)(bias + c0 + 64); }
#pragma unroll
    for (int i = 0; i < RPT; ++i) {
        int r = row0 + i;
        if (r < rows) {
            f4 v0, v1;
#pragma unroll
            for (int j = 0; j < 4; ++j) { v0[j] = acc[i][j] + bi0[j]; v1[j] = acc[i][j+4] + bi1[j]; }
            *(f4*)(out + (size_t)r * 128 + c0) = v0;
            *(f4*)(out + (size_t)r * 128 + c0 + 64) = v1;
        }
    }
}

// ================================================================ MFMA GEMM body (fp16 in, f32 acc)
// als/ald stored PRE-SCALED by log2(e). smem: 128*136*2 bytes.
template <typename AT>
__device__ __forceinline__ void gemm_mfma_body(int bid, const AT* __restrict__ A, int rows,
                                               const float* __restrict__ W, int ldw, int wcol0,
                                               const float* __restrict__ bias,
                                               const float* __restrict__ addtab,
                                               const int* __restrict__ addidx,
                                               const float* __restrict__ avs,
                                               const float* __restrict__ avd,
                                               float* __restrict__ als,
                                               float* __restrict__ ald,
                                               half_t* __restrict__ out16, char* smem) {
    half_t* Wl = (half_t*)smem;
    float*  Dl = (float*)smem;

    const int tid = threadIdx.x;
    const int row0 = bid * 64;

    for (int i = tid * 4; i < 128 * 128; i += 1024) {
        int c = i >> 7, k = i & 127;
        f4 wv = *(const f4*)(W + (size_t)c * ldw + wcol0 + k);
        h4v hv = {(half_t)wv[0], (half_t)wv[1], (half_t)wv[2], (half_t)wv[3]};
        *(h4v*)(Wl + c * 136 + k) = hv;
    }
    __syncthreads();

    const int wv_id = tid >> 6, l = tid & 63, lr = l & 15, lk = l >> 4;
    const int r_a = min(row0 + wv_id * 16 + lr, rows - 1);

    h8 af[4];
#pragma unroll
    for (int ks = 0; ks < 4; ++ks) {
        if constexpr (sizeof(AT) == 4) {
            f4 a0 = *(const f4*)(A + (size_t)r_a * 128 + ks * 32 + lk * 8);
            f4 a1 = *(const f4*)(A + (size_t)r_a * 128 + ks * 32 + lk * 8 + 4);
            h8 v = {(half_t)a0[0], (half_t)a0[1], (half_t)a0[2], (half_t)a0[3],
                    (half_t)a1[0], (half_t)a1[1], (half_t)a1[2], (half_t)a1[3]};
            af[ks] = v;
        } else {
            af[ks] = *(const h8*)(A + (size_t)r_a * 128 + ks * 32 + lk * 8);
        }
    }

    f4 acc[8];
#pragma unroll
    for (int t = 0; t < 8; ++t) acc[t] = (f4){0.f, 0.f, 0.f, 0.f};
#pragma unroll
    for (int ks = 0; ks < 4; ++ks) {
#pragma unroll
        for (int t = 0; t < 8; ++t) {
            h8 bf = *(const h8*)(Wl + (t * 16 + lr) * 136 + ks * 32 + lk * 8);
            acc[t] = __builtin_amdgcn_mfma_f32_16x16x32_f16(af[ks], bf, acc[t], 0, 0, 0);
        }
    }
    __syncthreads();

#pragma unroll
    for (int t = 0; t < 8; ++t)
#pragma unroll
        for (int q = 0; q < 4; ++q)
            Dl[(wv_id * 16 + lk * 4 + q) * 132 + t * 16 + lr] = acc[t][q];
    __syncthreads();

    const int cl = (tid & 15) * 8;
    f4 bi0 = {0.f,0.f,0.f,0.f}, bi1 = bi0;
    if (bias) { bi0 = *(const f4*)(bias + cl); bi1 = *(const f4*)(bias + cl + 4); }
    f4 as0 = {0.f,0.f,0.f,0.f}, as1 = as0, ad0 = as0, ad1 = as0;
    if (als) {
        as0 = *(const f4*)(avs + cl) * LOG2E; as1 = *(const f4*)(avs + cl + 4) * LOG2E;
        ad0 = *(const f4*)(avd + cl) * LOG2E; ad1 = *(const f4*)(avd + cl + 4) * LOG2E;
    }
#pragma unroll
    for (int pass = 0; pass < 4; ++pass) {
        int lrow = pass * 16 + (tid >> 4);
        int r = row0 + lrow;
        bool ok = r < rows;
        f4 v0 = *(const f4*)(Dl + lrow * 132 + cl);
        f4 v1 = *(const f4*)(Dl + lrow * 132 + cl + 4);
        v0 += bi0; v1 += bi1;
        if (addtab) {
            int ri = addidx[min(r, rows - 1)];
            v0 += *(const f4*)(addtab + (size_t)ri * 128 + cl);
            v1 += *(const f4*)(addtab + (size_t)ri * 128 + cl + 4);
        }
        if (als) {
            float ps = 0.f, pd = 0.f;
#pragma unroll
            for (int j = 0; j < 4; ++j) {
                ps += v0[j] * as0[j] + v1[j] * as1[j];
                pd += v0[j] * ad0[j] + v1[j] * ad1[j];
            }
            ps = row16_allred(ps);
            pd = row16_allred(pd);
            if ((tid & 15) == 0 && ok) { als[r] = ps; ald[r] = pd; }
        }
        if (ok) {
            h8 o = {(half_t)v0[0], (half_t)v0[1], (half_t)v0[2], (half_t)v0[3],
                    (half_t)v1[0], (half_t)v1[1], (half_t)v1[2], (half_t)v1[3]};
            *(h8*)(out16 + (size_t)r * 128 + cl) = o;
        }
    }
}

// ================================================================ entity body (FROZEN structure)
// Single caller (k_entity_fill) + __forceinline__: r20 showed a second caller
// breaks inlining -> VGPR 28->52, occupancy 70->38%, +11 µs. Keep ONE caller.
__device__ __forceinline__ void entity_body(int bid, const int* __restrict__ hA,
                                            const int* __restrict__ tA,
                                            const int* __restrict__ ridx,
                                            const half_t* __restrict__ pattr,
                                            const float* __restrict__ prel,
                                            half_t* __restrict__ s_emb16, int N) {
    int w = (bid * 256 + (int)threadIdx.x) >> 6;
    if (w >= N) return;
    w = __builtin_amdgcn_readfirstlane(w);
    const int lane = threadIdx.x & 63;
    const int c = lane * 2;
    const int ri = ridx[w];
    const f2 rp = *(const f2*)(prel + (size_t)ri * 128 + c);
    const h2 rph = {(half_t)(rp[0] * LOG2E), (half_t)(rp[1] * LOG2E)};
    const float init = (lane == 0) ? -ESHIFT2 : 0.f;
    const int* __restrict__ hp = hA + (size_t)w * 16;
    const int* __restrict__ tp = tA + (size_t)w * 16;
    const char* __restrict__ pb = (const char*)pattr;
    const unsigned cb = (unsigned)lane << 2;

    f2 oh = {0.f, 0.f}, ot = {0.f, 0.f};
    float sh = 0.f, st = 0.f;

    auto ld = [&](int idx) -> h2 {
        return *(const h2*)(pb + (((unsigned)idx << 8) + cb));
    };

    h2 bh[2][4], bt[2][4];
#pragma unroll
    for (int q = 0; q < 4; ++q) {
        bh[0][q] = ld(hp[q]);
        bt[0][q] = ld(tp[q]);
    }
#pragma unroll
    for (int b = 0; b < 4; ++b) {
        const int cur = b & 1, nxt = cur ^ 1;
        if (b < 3) {
#pragma unroll
            for (int q = 0; q < 4; ++q) {
                bh[nxt][q] = ld(hp[4 * (b + 1) + q]);
                bt[nxt][q] = ld(tp[4 * (b + 1) + q]);
            }
        }
        float pph[4], ppt[4];
#pragma unroll
        for (int q = 0; q < 4; ++q) {
            pph[q] = __builtin_amdgcn_fdot2(rph, bh[cur][q], init, false);
            ppt[q] = __builtin_amdgcn_fdot2(rph, bt[cur][q], init, false);
        }
        float Sh[4], St[4];
#pragma unroll
        for (int q = 0; q < 4; ++q) {
            Sh[q] = wave_red_bcast(pph[q]);
            St[q] = wave_red_bcast(ppt[q]);
        }
#pragma unroll
        for (int q = 0; q < 4; ++q) {
            float wh = EXP2(Sh[q]);
            float wt = EXP2(St[q]);
            sh += wh; st += wt;
            oh[0] = fmaf(wh, (float)bh[cur][q][0], oh[0]);
            oh[1] = fmaf(wh, (float)bh[cur][q][1], oh[1]);
            ot[0] = fmaf(wt, (float)bt[cur][q][0], ot[0]);
            ot[1] = fmaf(wt, (float)bt[cur][q][1], ot[1]);
        }
    }
    float invh = 1.f / sh, invt = 1.f / st;
    h2 hv = {(half_t)(oh[0] * invh + ot[0] * invt),
             (half_t)(oh[1] * invh + ot[1] * invt)};
    *(h2*)(s_emb16 + (size_t)w * 128 + c) = hv;
}

// ================================================================ fused dispatch kernels (r17 set — exact)
// L1: attr-table MFMA projection (blocks FIRST — compute-critical)  ∥  CSR count+rank
__global__ __launch_bounds__(256) void k_attr_count(const float* __restrict__ attr, int NA,
                                                    const float* __restrict__ W,
                                                    const float* __restrict__ bias,
                                                    half_t* __restrict__ out16, int MB,
                                                    const int* __restrict__ ei, int E, int N,
                                                    int* __restrict__ cnt,
                                                    int* __restrict__ rank) {
    __shared__ alignas(16) char smem[128 * 136 * 2];
    int b = blockIdx.x;
    if (b < MB) gemm_mfma_body<float>(b, attr, NA, W, DE, 0, bias, nullptr, nullptr,
                                      nullptr, nullptr, nullptr, nullptr, out16, smem);
    else count_body(b - MB, ei, E, N, cnt, rank);
}

// L2: rel-table GEMMs (both)  ∥  CSR scan
__global__ __launch_bounds__(256) void k_rel_scan(const float* __restrict__ in, int rows,
                                                  const float* __restrict__ W1,
                                                  const float* __restrict__ b1,
                                                  float* __restrict__ out1,
                                                  const float* __restrict__ W2,
                                                  float* __restrict__ out2, int RB,
                                                  const int* __restrict__ cnt, int n,
                                                  int* __restrict__ indptr) {
    __shared__ alignas(16) char smem[128 * 128 * 4];  // rel Wt (64KB); scan uses first 20B
    int b = blockIdx.x;
    if (b < 2 * RB) rel_body(b % RB, b / RB, in, rows, W1, b1, out1, W2, out2, smem);
    else scan_body(cnt, n, indptr, smem);
}

// L3: entity attention (blocks FIRST — latency-critical)  ∥  atomic-free CSR fill
__global__ __launch_bounds__(256) void k_entity_fill(const int* __restrict__ hA,
                                                     const int* __restrict__ tA,
                                                     const int* __restrict__ ridx,
                                                     const half_t* __restrict__ pattr,
                                                     const float* __restrict__ prel,
                                                     half_t* __restrict__ s_emb16, int N, int EB,
                                                     const int* __restrict__ ei, int E,
                                                     const int* __restrict__ indptr,
                                                     const int* __restrict__ rank,
                                                     int* __restrict__ adj) {
    int b = blockIdx.x;
    if (b < EB) entity_body(b, hA, tA, ridx, pattr, prel, s_emb16, N);
    else fill_body(b - EB, ei, E, N, indptr, rank, adj);
}

// standalone MFMA GEMM (gat layers)
__global__ __launch_bounds__(256) void k_gemm_mfma_h(const half_t* __restrict__ A, int rows,
                                                     const float* __restrict__ W, int ldw, int wcol0,
                                                     const float* __restrict__ bias,
                                                     const float* __restrict__ addtab,
                                                     const int* __restrict__ addidx,
                                                     const float* __restrict__ avs,
                                                     const float* __restrict__ avd,
                                                     float* __restrict__ als,
                                                     float* __restrict__ ald,
                                                     half_t* __restrict__ out16) {
    __shared__ alignas(16) char smem[128 * 136 * 2];
    gemm_mfma_body<half_t>(blockIdx.x, A, rows, W, ldw, wcol0, bias, addtab, addidx,
                           avs, avd, als, ald, out16, smem);
}

// ---------------------------------------------------------------- GAT aggregate (CSR, r17 form — FROZEN)
__global__ __launch_bounds__(256) void k_aggregate(const int* __restrict__ indptr,
                                                   const int* __restrict__ adj,
                                                   const half_t* __restrict__ hsrc,
                                                   const float* __restrict__ als,
                                                   const float* __restrict__ ald,
                                                   const float* __restrict__ bias,
                                                   float* __restrict__ out,
                                                   half_t* __restrict__ out16, int N) {
    const int tid = threadIdx.x;
    const int wv = (blockIdx.x * 256 + tid) >> 6;
    const int nodeA = wv * 2;
    if (nodeA >= N) return;
    const int lane = tid & 63;
    const int node = min(nodeA + (lane >> 5), N - 1);
    const int sl = lane & 31;
    const int c = sl * 4;

    const int beg = indptr[node];
    const int deg = indptr[node + 1] - beg;   // >= 1 (self-loop)
    const float adn = ald[node];              // pre-scaled by log2(e)
    const char* __restrict__ hb = (const char*)hsrc;
    const unsigned cb = (unsigned)sl << 3;

    float acc[4] = {0.f, 0.f, 0.f, 0.f};
    float exsum = 0.f;

    int cur[8], nxt[8];
#pragma unroll
    for (int q = 0; q < 8; ++q) cur[q] = adj[beg + q];  // batch 0 (padded)

#pragma unroll 1
    for (int j0 = 0; j0 < deg; j0 += 8) {
        if (j0 + 8 < deg) {
#pragma unroll
            for (int q = 0; q < 8; ++q) nxt[q] = adj[beg + j0 + 8 + q];
        }
        int ss[8];
        float alv[8];
        h4v hv[8];
#pragma unroll
        for (int q = 0; q < 8; ++q)
            ss[q] = ((unsigned)cur[q] < (unsigned)N) ? cur[q] : 0;
#pragma unroll
        for (int q = 0; q < 8; ++q) alv[q] = als[ss[q]];
#pragma unroll
        for (int q = 0; q < 8; ++q)
            hv[q] = *(const h4v*)(hb + (((unsigned)ss[q] << 8) + cb));
#pragma unroll
        for (int q = 0; q < 8; ++q) {
            bool ok = (j0 + q) < deg;
            float e = alv[q] + adn;
            e = fmaxf(e, NEG_SLOPE * e);
            float ex = ok ? EXP2(e - ESHIFT_AGG) : 0.f;
            exsum += ex;
#pragma unroll
            for (int j = 0; j < 4; ++j) acc[j] = fmaf(ex, (float)hv[q][j], acc[j]);
        }
#pragma unroll
        for (int q = 0; q < 8; ++q) cur[q] = nxt[q];
    }

    float inv = 1.f / exsum;
    if (out) {
        f4 o;
#pragma unroll
        for (int j = 0; j < 4; ++j) o[j] = fmaf(acc[j], inv, bias[c + j]);
        *(f4*)(out + (size_t)node * 128 + c) = o;
    } else {
        h4v o;
#pragma unroll
        for (int j = 0; j < 4; ++j) o[j] = (half_t)fmaf(acc[j], inv, bias[c + j]);
        *(h4v*)(out16 + (size_t)node * 128 + c) = o;
    }
}

// ---------------------------------------------------------------- launch (r17 schedule — exact)
extern "C" void kernel_launch(void* const* d_in, const int* in_sizes, int n_in,
                              void* d_out, int out_size, void* d_ws, size_t ws_size,
                              hipStream_t stream) {
    const int*   hA   = (const int*)d_in[0];
    const int*   tA   = (const int*)d_in[1];
    const int*   rix  = (const int*)d_in[2];
    const int*   ei   = (const int*)d_in[3];
    const float* attr_table = (const float*)d_in[4];
    const float* rel_table  = (const float*)d_in[5];
    const float* femb_w = (const float*)d_in[6];
    const float* femb_b = (const float*)d_in[7];
    const float* g1w  = (const float*)d_in[8];
    const float* g1as = (const float*)d_in[9];
    const float* g1ad = (const float*)d_in[10];
    const float* g1b  = (const float*)d_in[11];
    const float* g2w  = (const float*)d_in[12];
    const float* g2as = (const float*)d_in[13];
    const float* g2ad = (const float*)d_in[14];
    const float* g2b  = (const float*)d_in[15];

    const int N  = in_sizes[2];
    const int E  = in_sizes[3] / 2;
    const int NA = in_sizes[4] / DE;
    const int NR = in_sizes[5] / DE;
    const int EN = E + N;

    char* p = (char*)d_ws;
    auto alloc = [&](size_t bytes) -> char* {
        char* q = p;
        p += (bytes + 255) & ~(size_t)255;
        return q;
    };
    half_t* proj16 = (half_t*)alloc((size_t)NA * DE * 2);
    half_t* s16    = (half_t*)alloc((size_t)N * DE * 2);
    half_t* h16    = (half_t*)alloc((size_t)N * DE * 2);
    half_t* x116   = (half_t*)alloc((size_t)N * DE * 2);
    float* prel    = (float*)alloc((size_t)NR * DE * 4);
    float* rel2    = (float*)alloc((size_t)NR * DE * 4);
    float* alps    = (float*)alloc((size_t)N * 4);
    float* alpd    = (float*)alloc((size_t)N * 4);
    int*   indptr  = (int*)alloc((size_t)(N + 1) * 4);
    int*   cnt     = (int*)alloc((size_t)N * 4);
    int*   rank    = (int*)alloc((size_t)EN * 4);
    int*   adj     = (int*)alloc((size_t)(EN + 16) * 4);  // +16 pad for batch-8 over-read

    dim3 b256(256);
    const int CB = (EN + 255) / 256;         // count/fill blocks
    const int MB = (NA + 63) / 64;           // attr mfma blocks
    const int RB = (NR + 31) / 32;           // rel gemm blocks (per W)
    const int GB = (N + 63) / 64;            // gat gemm blocks
    const int EB = (N + 3) / 4;              // entity blocks

    hipMemsetAsync(cnt, 0, (size_t)N * 4, stream);

    // L1: attr MFMA (first) ∥ CSR count (+rank record)
    k_attr_count<<<dim3(MB + CB), b256, 0, stream>>>(attr_table, NA, femb_w, femb_b,
                                                     proj16, MB, ei, E, N, cnt, rank);

    // L2: rel-table GEMMs ∥ CSR scan
    k_rel_scan<<<dim3(2 * RB + 1), b256, 0, stream>>>(rel_table, NR, femb_w, femb_b, prel,
                                                      g1w, rel2, RB, cnt, N, indptr);

    // L3: entity (first) ∥ atomic-free fill
    k_entity_fill<<<dim3(EB + CB), b256, 0, stream>>>(hA, tA, rix, proj16, prel, s16, N, EB,
                                                      ei, E, indptr, rank, adj);

    // L4: GAT-1 GEMM standalone (alpha fused, pre-scaled; h fp16)
    k_gemm_mfma_h<<<dim3(GB), b256, 0, stream>>>(s16, N,
        g1w, 2 * DE, 0, nullptr, rel2, rix, g1as, g1ad, alps, alpd, h16);

    k_aggregate<<<dim3((N + 7) / 8), b256, 0, stream>>>(indptr, adj, h16, alps, alpd, g1b,
                                                        nullptr, x116, N);

    // GAT layer 2
    k_gemm_mfma_h<<<dim3(GB), b256, 0, stream>>>(x116, N,
        g2w, DE, 0, nullptr, nullptr, nullptr, g2as, g2ad, alps, alpd, h16);
    k_aggregate<<<dim3((N + 7) / 8), b256, 0, stream>>>(indptr, adj, h16, alps, alpd, g2b,
                                                        (float*)d_out, nullptr, N);
}